// Round 1
// baseline (270.466 us; speedup 1.0000x reference)
//
#include <hip/hip_runtime.h>

// DualModel3: fused fc head + 4096 tiny decoder MLPs on MI355X (gfx950).
// B=256, IN=2048, NC=1000, O=4096, H=4.
//
// Strategy: one bf16-MFMA GEMM kernel over the concatenated column space.
//   blocks 0..15   : fc head, columns of fcW (N=1000, padded to 1024)
//   blocks 16..271 : decoders, columns c = o*4+h of W1 viewed as [IN, O*H]
// BM=256 (whole batch per block -> W1 streamed from HBM exactly once),
// BN=64, BK=32, mfma_f32_16x16x32_bf16, 4 waves x (4m x 4n) tiles.
// Decoder epilogue fuses bias + leaky-relu + W2-weighted H-reduction via
// __shfl_xor over the 4 adjacent lanes holding one decoder's h-columns
// (C/D layout: col = lane&15, row = (lane>>4)*4 + reg  [m89-verified]).

typedef __bf16 bf16_t;
typedef __bf16 bf16x8 __attribute__((ext_vector_type(8)));
typedef __bf16 bf16x4 __attribute__((ext_vector_type(4)));
typedef float  f32x4  __attribute__((ext_vector_type(4)));

#define LDS_STRIDE 40   // bf16 elems per row: 80 B, 16B-aligned, 20-bank stride (2-way only)

__global__ __launch_bounds__(256, 2)
void fused_dual(const float* __restrict__ x,    // [256,2048]
                const float* __restrict__ fcW,  // [1000,2048]
                const float* __restrict__ fcb,  // [1000]
                const float* __restrict__ W1,   // [4096,2048,4] flat
                const float* __restrict__ b1,   // [4096,4] flat
                const float* __restrict__ W2,   // [4096,4] flat
                const float* __restrict__ b2,   // [4096]
                float* __restrict__ out)        // x1 [256*1000] ++ x2 [256*4096]
{
    __shared__ bf16_t lA[256 * LDS_STRIDE];   // 20480 B
    __shared__ bf16_t lB[64  * LDS_STRIDE];   // 5120 B

    const int tid   = threadIdx.x;
    const int blk   = blockIdx.x;
    const bool is_fc = (blk < 16);
    const int c0    = (is_fc ? blk : (blk - 16)) * 64;

    // ---- staging index assignment ----
    // A tile [256 rows x 32 k]: thread t -> col4 = t&7 (4 floats), rows t>>3 + 32*r
    const int a_col4 = tid & 7;
    const int a_r0   = tid >> 3;
    // B tile [64 n x 32 k]: thread t -> n = t>>2, k-block = t&3 (8 k's)
    const int b_n    = tid >> 2;
    const int b_kb   = tid & 3;

    const float* ap = x + a_r0 * 2048 + a_col4 * 4;
    const float* bp;
    if (is_fc) {
        int row = c0 + b_n; if (row > 999) row = 999;   // clamp; cols >=1000 never stored
        bp = fcW + row * 2048 + b_kb * 8;
    } else {
        // W1 flat addr = o*8192 + i*4 + h ; column c = o*4+h, k = i
        const int o = (c0 >> 2) + (b_n >> 2);
        bp = W1 + o * 8192 + b_kb * 32 + (b_n & 3);
    }

    float4 aR[8];
    float  bR[8];

    // prologue loads (kt = 0)
    #pragma unroll
    for (int r = 0; r < 8; ++r) aR[r] = *(const float4*)(ap + r * (32 * 2048));
    if (is_fc) {
        float4 t0 = *(const float4*)bp;
        float4 t1 = *(const float4*)(bp + 4);
        bR[0] = t0.x; bR[1] = t0.y; bR[2] = t0.z; bR[3] = t0.w;
        bR[4] = t1.x; bR[5] = t1.y; bR[6] = t1.z; bR[7] = t1.w;
    } else {
        #pragma unroll
        for (int j = 0; j < 8; ++j) bR[j] = bp[j * 4];  // stride 16B; line-filling over j
    }

    const int wav  = tid >> 6;
    const int lane = tid & 63;
    const int l15  = lane & 15;
    const int quad = lane >> 4;

    f32x4 acc[4][4];
    #pragma unroll
    for (int i = 0; i < 4; ++i)
        #pragma unroll
        for (int j = 0; j < 4; ++j) acc[i][j] = (f32x4){0.f, 0.f, 0.f, 0.f};

    char* lAb = (char*)lA;
    char* lBb = (char*)lB;
    const int aWbase = a_r0 * (LDS_STRIDE * 2) + a_col4 * 8;
    const int bWbase = b_n  * (LDS_STRIDE * 2) + b_kb * 16;

    for (int kt = 0; kt < 64; ++kt) {
        __syncthreads();                       // previous iter's LDS reads done
        // ---- cvt + write LDS ----
        #pragma unroll
        for (int r = 0; r < 8; ++r) {
            bf16x4 v;
            v[0] = (bf16_t)aR[r].x; v[1] = (bf16_t)aR[r].y;
            v[2] = (bf16_t)aR[r].z; v[3] = (bf16_t)aR[r].w;
            *(bf16x4*)(lAb + aWbase + r * (32 * LDS_STRIDE * 2)) = v;
        }
        {
            bf16x8 v;
            #pragma unroll
            for (int j = 0; j < 8; ++j) v[j] = (bf16_t)bR[j];
            *(bf16x8*)(lBb + bWbase) = v;
        }
        __syncthreads();                       // LDS tile visible
        // ---- prefetch next tile into regs (overlaps MFMA below) ----
        if (kt != 63) {
            ap += 32;
            bp += is_fc ? 32 : 128;
            #pragma unroll
            for (int r = 0; r < 8; ++r) aR[r] = *(const float4*)(ap + r * (32 * 2048));
            if (is_fc) {
                float4 t0 = *(const float4*)bp;
                float4 t1 = *(const float4*)(bp + 4);
                bR[0] = t0.x; bR[1] = t0.y; bR[2] = t0.z; bR[3] = t0.w;
                bR[4] = t1.x; bR[5] = t1.y; bR[6] = t1.z; bR[7] = t1.w;
            } else {
                #pragma unroll
                for (int j = 0; j < 8; ++j) bR[j] = bp[j * 4];
            }
        }
        // ---- fragments + MFMA ----
        // A[m = lane&15][k = quad*8 + j], B[k = quad*8 + j][n = lane&15]
        bf16x8 af[4], bfr[4];
        #pragma unroll
        for (int mt = 0; mt < 4; ++mt)
            af[mt] = *(const bf16x8*)(lAb + (wav * 64 + mt * 16 + l15) * (LDS_STRIDE * 2) + quad * 16);
        #pragma unroll
        for (int nt = 0; nt < 4; ++nt)
            bfr[nt] = *(const bf16x8*)(lBb + (nt * 16 + l15) * (LDS_STRIDE * 2) + quad * 16);
        #pragma unroll
        for (int mt = 0; mt < 4; ++mt)
            #pragma unroll
            for (int nt = 0; nt < 4; ++nt)
                acc[mt][nt] = __builtin_amdgcn_mfma_f32_16x16x32_bf16(af[mt], bfr[nt], acc[mt][nt], 0, 0, 0);
    }

    // ---- epilogue ----
    if (is_fc) {
        #pragma unroll
        for (int nt = 0; nt < 4; ++nt) {
            const int c = c0 + nt * 16 + l15;
            const bool valid = (c < 1000);
            const float bias = valid ? fcb[c] : 0.f;
            #pragma unroll
            for (int mt = 0; mt < 4; ++mt) {
                #pragma unroll
                for (int r = 0; r < 4; ++r) {
                    if (valid) {
                        const int row = wav * 64 + mt * 16 + quad * 4 + r;
                        out[row * 1000 + c] = acc[mt][nt][r] + bias;
                    }
                }
            }
        }
    } else {
        float* x2out = out + 256 * 1000;
        #pragma unroll
        for (int nt = 0; nt < 4; ++nt) {
            const int c   = c0 + nt * 16 + l15;   // global column in [0,16384)
            const float b1v = b1[c];
            const float w2v = W2[c];
            const int o   = c >> 2;
            const float b2v = b2[o];
            #pragma unroll
            for (int mt = 0; mt < 4; ++mt) {
                #pragma unroll
                for (int r = 0; r < 4; ++r) {
                    float h = acc[mt][nt][r] + b1v;
                    h = (h >= 0.f) ? h : 0.1f * h;      // leaky relu, NEG_SLOPE=0.1
                    float wv = h * w2v;
                    // sum the 4 h-columns of this decoder (adjacent lanes, same row)
                    wv += __shfl_xor(wv, 1, 64);
                    wv += __shfl_xor(wv, 2, 64);
                    if ((lane & 3) == 0) {
                        const int row = wav * 64 + mt * 16 + quad * 4 + r;
                        x2out[row * 4096 + o] = wv + b2v;
                    }
                }
            }
        }
    }
}

extern "C" void kernel_launch(void* const* d_in, const int* in_sizes, int n_in,
                              void* d_out, int out_size, void* d_ws, size_t ws_size,
                              hipStream_t stream)
{
    (void)in_sizes; (void)n_in; (void)d_ws; (void)ws_size; (void)out_size;
    const float* x   = (const float*)d_in[0];
    const float* fcW = (const float*)d_in[1];
    const float* fcb = (const float*)d_in[2];
    const float* W1  = (const float*)d_in[3];
    const float* b1  = (const float*)d_in[4];
    const float* W2  = (const float*)d_in[5];
    const float* b2  = (const float*)d_in[6];
    fused_dual<<<272, 256, 0, stream>>>(x, fcW, fcb, W1, b1, W2, b2, (float*)d_out);
}